// Round 4
// baseline (391.230 us; speedup 1.0000x reference)
//
#include <hip/hip_runtime.h>
#include <math.h>

// MoE router: T=16384 tokens, H=4096, E=8 experts, K=2.
// d_out layout (float32, flat, reference return order):
//   [0      , 32768 )  routing_weights  (T,2)
//   [32768  , 65536 )  selected_experts (T,2)  stored as float(index)
//   [65536  , 196608)  router_logits    (T,8)
//   [196608 ]          aux_loss (scalar)
// d_ws: 16 rows x NBLOCKS of per-block partials (plain stores, no init):
//   row e   (e=0..7):  sum of softmax probs for expert e
//   row 8+e (e=0..7):  top-1 counts for expert e
//
// R4 change: gate matrix -> LDS. R3's router (~75us inferred) ran at 57% of
// achievable BW. Root causes, all from gate living in global memory:
// (1) vmcnt is FIFO: consuming the 8 gate loads each chunk forced draining
//     the hidden A/B prefetch too (issued earlier in program order) ->
//     effective prefetch distance 0, exposed DRAM latency every chunk.
// (2) gate re-read per wave per k-loop = 512 MB via L1/L2, 2x the payload.
// Fix: 1024-thread blocks (16 waves, grid=256 = exactly 1 block/CU), stage
// the full 128 KB gate into LDS once, read it with conflict-free contiguous
// ds_read_b128 (lgkmcnt — separate counter, hidden prefetch rides vmcnt
// undisturbed). Hidden loads revert to plain (non-NT): L2-protection of gate
// is moot now, and the 6.29 TB/s ubench used plain float4.
// VGPR budget: 1024-thread block => 4 waves/SIMD resident => hard cap 128
// (launch_bounds(1024,4)). Demand ~110: acc 32 + hvA/B 32 + gate 32 + addr.

#define T_TOKENS 16384
#define H_DIM    4096
#define NEXP     8
#define H4       (H_DIM / 4)   // 1024 float4 per row
#define ITERS    (H4 / 64)     // 16 float4 chunks per lane per token
#define TOK_PER_WAVE 4
#define WAVES_PER_BLOCK 16
#define TOK_PER_BLOCK (TOK_PER_WAVE * WAVES_PER_BLOCK)  // 64
#define NBLOCKS (T_TOKENS / TOK_PER_BLOCK)              // 256

#define OFF_RW  0
#define OFF_SE  32768
#define OFF_LG  65536
#define OFF_AUX 196608

// Native vector type (HIP's float4 is a class; ext_vector works everywhere).
typedef float vfloat4 __attribute__((ext_vector_type(4)));

// Halving butterfly step: value set of size 2N -> N, summing over lane pairs
// differing in bit OFFSET. Starting from 32 values r[0..31] and steps
// OFFSET=16,8,4,2,1, lane l ends holding the 32-lane-half sum of value (l&31).
#define RED_STEP(OFFSET, N)                                        \
  {                                                                \
    const bool hi = (lane & (OFFSET)) != 0;                        \
    _Pragma("unroll")                                              \
    for (int i = 0; i < (N); ++i) {                                \
      float send = hi ? r[i] : r[i + (N)];                         \
      float recv = __shfl_xor(send, (OFFSET), 64);                 \
      r[i] = (hi ? r[i + (N)] : r[i]) + recv;                      \
    }                                                              \
  }

// Issue the 4 hidden loads for chunk KIDX into a named register buffer.
// Plain loads (vmcnt); the only vmcnt traffic in the k-loop, so the A/B
// prefetch is never drained by anything else.
#define LOAD_H(HV, KIDX)                                           \
  {                                                                \
    const int idx_ = lane + 64 * (KIDX);                           \
    _Pragma("unroll")                                              \
    for (int t = 0; t < TOK_PER_WAVE; ++t)                         \
      HV[t] = h4p[(tokenBase + t) * H4 + idx_];                    \
  }

// Read this chunk's 8 gate float4s from LDS (contiguous ds_read_b128,
// conflict-free, lgkmcnt) and do the 128 FMAs.
#define GATE_AND_COMPUTE(HV, KIDX)                                 \
  {                                                                \
    const int idx_ = lane + 64 * (KIDX);                           \
    vfloat4 g[NEXP];                                               \
    _Pragma("unroll")                                              \
    for (int e = 0; e < NEXP; ++e) g[e] = smG4[e * H4 + idx_];     \
    _Pragma("unroll")                                              \
    for (int t = 0; t < TOK_PER_WAVE; ++t) {                       \
      _Pragma("unroll")                                            \
      for (int e = 0; e < NEXP; ++e) {                             \
        float a = r[t * NEXP + e];                                 \
        a = fmaf(HV[t].x, g[e].x, a);                              \
        a = fmaf(HV[t].y, g[e].y, a);                              \
        a = fmaf(HV[t].z, g[e].z, a);                              \
        a = fmaf(HV[t].w, g[e].w, a);                              \
        r[t * NEXP + e] = a;                                       \
      }                                                            \
    }                                                              \
  }

__global__ __launch_bounds__(1024, 4)
void router_kernel(const float* __restrict__ hs, const float* __restrict__ gw,
                   float* __restrict__ out, float* __restrict__ ws) {
  // Full gate matrix in LDS: 8 x 1024 float4 = 128 KB (of 160 KB/CU).
  __shared__ vfloat4 smG4[NEXP * H4];
  __shared__ float smP[NEXP];
  __shared__ float smC[NEXP];

  const vfloat4* __restrict__ h4p = reinterpret_cast<const vfloat4*>(hs);
  const vfloat4* __restrict__ g4p = reinterpret_cast<const vfloat4*>(gw);

  if (threadIdx.x < NEXP) { smP[threadIdx.x] = 0.f; smC[threadIdx.x] = 0.f; }
  // Cooperative gate stage: 1024 threads x 8 float4 = 8192 float4 = 128 KB.
#pragma unroll
  for (int i = 0; i < 8; ++i)
    smG4[threadIdx.x + 1024 * i] = g4p[threadIdx.x + 1024 * i];
  __syncthreads();

  const int lane = threadIdx.x & 63;
  const int wave = threadIdx.x >> 6;
  const int tokenBase = (blockIdx.x * WAVES_PER_BLOCK + wave) * TOK_PER_WAVE;

  float r[TOK_PER_WAVE * NEXP];  // 32 accumulators: r[t*8+e]
#pragma unroll
  for (int i = 0; i < TOK_PER_WAVE * NEXP; ++i) r[i] = 0.f;

  // Depth-1 pipeline on the hidden stream. Named A/B buffers with a k+=2
  // loop: every register access is compile-time-indexed.
  vfloat4 hvA[TOK_PER_WAVE], hvB[TOK_PER_WAVE];

  LOAD_H(hvA, 0)
  for (int k = 0; k < ITERS; k += 2) {
    LOAD_H(hvB, k + 1)              // prefetch odd hidden chunk (vmcnt)
    GATE_AND_COMPUTE(hvA, k)        // gate via LDS (lgkmcnt) + FMAs
    if (k + 2 < ITERS) {
      LOAD_H(hvA, k + 2)            // prefetch next even hidden chunk
    }
    GATE_AND_COMPUTE(hvB, k + 1)
  }

  // 32-value butterfly within each 32-lane half: lane l ends holding the
  // half-sum of value (l&31) (token = (l&31)>>3, expert = l&7).
  RED_STEP(16, 16)
  RED_STEP(8, 8)
  RED_STEP(4, 4)
  RED_STEP(2, 2)
  float red;
  {
    const bool hi = (lane & 1) != 0;
    float send = hi ? r[0] : r[1];
    float recv = __shfl_xor(send, 1, 64);
    red = (hi ? r[1] : r[0]) + recv;
  }
  // Fold the two 32-lane halves: every lane now holds the full 64-lane sum
  // of value (lane&31).
  red += __shfl_xor(red, 32, 64);

  // Lanes 0..31 store one logit each: 128 B contiguous per wave.
  if (lane < 32) out[OFF_LG + tokenBase * NEXP + lane] = red;

  // Gather the 8 logits of this lane-group's token (source lanes 0..31 hold
  // full sums; all 64 lanes execute the shfl).
  float le[NEXP];
  const int groupBase = lane & 24;
#pragma unroll
  for (int e = 0; e < NEXP; ++e) le[e] = __shfl(red, groupBase + e, 64);

  if (lane < 32 && (lane & 7) == 0) {
    const int tok = tokenBase + (lane >> 3);
    // top-1 (strict > => lowest index wins ties, like lax.top_k)
    int i1 = 0; float m1 = le[0];
#pragma unroll
    for (int e = 1; e < NEXP; ++e) {
      if (le[e] > m1) { m1 = le[e]; i1 = e; }
    }
    int i2 = (i1 == 0) ? 1 : 0; float m2 = le[i2];
#pragma unroll
    for (int e = 0; e < NEXP; ++e) {
      if (e != i1 && le[e] > m2) { m2 = le[e]; i2 = e; }
    }
    // full softmax (max-shifted)
    float p[NEXP];
    float psum = 0.f;
#pragma unroll
    for (int e = 0; e < NEXP; ++e) { p[e] = expf(le[e] - m1); psum += p[e]; }
    const float inv = 1.0f / psum;
#pragma unroll
    for (int e = 0; e < NEXP; ++e) atomicAdd(&smP[e], p[e] * inv);
    atomicAdd(&smC[i1], 1.0f);

    // normalized top-2 routing weights: p[i1] = 1, p[i2] = exp(m2-m1)
    const float w1 = p[i1], w2 = p[i2];
    const float rs = 1.0f / (w1 + w2);
    out[OFF_RW + tok * 2 + 0] = w1 * rs;
    out[OFF_RW + tok * 2 + 1] = w2 * rs;
    out[OFF_SE + tok * 2 + 0] = (float)i1;
    out[OFF_SE + tok * 2 + 1] = (float)i2;
  }

  __syncthreads();
  // Per-block partials: row-major [16 rows][NBLOCKS]; plain stores, no
  // init needed (d_ws is poison — we overwrite every slot we later read).
  if (threadIdx.x < 2 * NEXP) {
    const float v = (threadIdx.x < NEXP) ? smP[threadIdx.x]
                                         : smC[threadIdx.x - NEXP];
    ws[threadIdx.x * NBLOCKS + blockIdx.x] = v;
  }
}

__global__ __launch_bounds__(1024)
void aux_kernel(const float* __restrict__ ws, float* __restrict__ out) {
  __shared__ float sm[2 * NEXP];
  const int lane = threadIdx.x & 63;
  const int w = threadIdx.x >> 6;  // 16 waves, one per partial row
  float s = 0.f;
#pragma unroll
  for (int i = 0; i < NBLOCKS / 64; ++i) s += ws[w * NBLOCKS + lane + 64 * i];
#pragma unroll
  for (int off = 32; off > 0; off >>= 1) s += __shfl_xor(s, off, 64);
  if (lane == 0) sm[w] = s;
  __syncthreads();
  if (threadIdx.x == 0) {
    const float invT = 1.0f / (float)T_TOKENS;
    float acc = 0.f;
#pragma unroll
    for (int e = 0; e < NEXP; ++e) {
      const float f = sm[NEXP + e] * invT;  // mean one-hot(top1)
      const float P = sm[e] * invT;         // mean probs
      acc += f * P;
    }
    out[OFF_AUX] = 0.01f * (float)NEXP * acc;
  }
}

extern "C" void kernel_launch(void* const* d_in, const int* in_sizes, int n_in,
                              void* d_out, int out_size, void* d_ws, size_t ws_size,
                              hipStream_t stream) {
  const float* hs = (const float*)d_in[0];   // (16384, 4096) f32
  const float* gw = (const float*)d_in[1];   // (8, 4096) f32
  float* out = (float*)d_out;
  float* ws  = (float*)d_ws;

  router_kernel<<<NBLOCKS, 1024, 0, stream>>>(hs, gw, out, ws);
  aux_kernel<<<1, 1024, 0, stream>>>(ws, out);
}

// Round 5
// 361.338 us; speedup vs baseline: 1.0827x; 1.0827x over previous
//
#include <hip/hip_runtime.h>
#include <math.h>

// MoE router: T=16384 tokens, H=4096, E=8 experts, K=2.
// d_out layout (float32, flat, reference return order):
//   [0      , 32768 )  routing_weights  (T,2)
//   [32768  , 65536 )  selected_experts (T,2)  stored as float(index)
//   [65536  , 196608)  router_logits    (T,8)
//   [196608 ]          aux_loss (scalar)
// d_ws: 16 rows x NBLOCKS of per-block partials (plain stores, no init).
//
// R5 change: deep async hidden prefetch via global_load_lds. R3 (~75us) and
// R4 (~112us) were both MLP-bound: per-CU in-flight bytes were 4 KB / 2 KB
// vs the ~9-22 KB BW*latency product, because register prefetch costs 4 VGPR
// per in-flight float4. global_load_lds queues on vmcnt with zero VGPR cost.
// Per-wave private 2-buffer LDS ring (2 x 4 KB), no k-loop barriers, manual
// counted vmcnt discipline (never 0 in steady state):
//   iter k: gate loads (L2) | ds_read chunk k | lgkmcnt(0) (WAR fence) |
//           stage k+2 into same buffer | vmcnt(4) (gate_k + stage_{k+1}
//           done, stage_{k+2} in flight) | 128 FMAs.
// In-flight ~8-12 KB/wave x 16 waves/CU >> 9 KB needed -> DRAM saturated.
// VGPR ~100 under launch_bounds(256,4) cap 128 (slack ~25; R2's spill was a
// 160-demand-under-170-cap squeeze). LDS 32.06 KB -> 4 blocks/CU.

#define T_TOKENS 16384
#define H_DIM    4096
#define NEXP     8
#define H4       (H_DIM / 4)   // 1024 float4 per row
#define ITERS    (H4 / 64)     // 16 float4 chunks per lane per token
#define TOK_PER_WAVE 4
#define WAVES_PER_BLOCK 4
#define TOK_PER_BLOCK (TOK_PER_WAVE * WAVES_PER_BLOCK)  // 16
#define NBLOCKS (T_TOKENS / TOK_PER_BLOCK)              // 1024

#define OFF_RW  0
#define OFF_SE  32768
#define OFF_LG  65536
#define OFF_AUX 196608

// Native vector type (HIP's float4 is a class; ext_vector works everywhere).
typedef float vfloat4 __attribute__((ext_vector_type(4)));

// Halving butterfly step: value set of size 2N -> N, summing over lane pairs
// differing in bit OFFSET. Starting from 32 values r[0..31] and steps
// OFFSET=16,8,4,2,1, lane l ends holding the 32-lane-half sum of value (l&31).
#define RED_STEP(OFFSET, N)                                        \
  {                                                                \
    const bool hi = (lane & (OFFSET)) != 0;                        \
    _Pragma("unroll")                                              \
    for (int i = 0; i < (N); ++i) {                                \
      float send = hi ? r[i] : r[i + (N)];                         \
      float recv = __shfl_xor(send, (OFFSET), 64);                 \
      r[i] = (hi ? r[i + (N)] : r[i]) + recv;                      \
    }                                                              \
  }

// Async-stage the 4 hidden float4-chunks for chunk KIDX into LDS buffer BUF.
// LDS dest is the wave-uniform row base; HW scatters lane l to base + l*16.
// Global source is per-lane. Zero VGPR cost for the in-flight data.
#define STAGE(BUF, KIDX)                                                    \
  {                                                                         \
    _Pragma("unroll")                                                       \
    for (int t = 0; t < TOK_PER_WAVE; ++t)                                  \
      __builtin_amdgcn_global_load_lds(                                     \
          (const __attribute__((address_space(1))) void*)                   \
              &h4p[(tokenBase + t) * H4 + lane + 64 * (KIDX)],              \
          (__attribute__((address_space(3))) void*)&tile[wave][BUF][t][0],  \
          16, 0, 0);                                                        \
  }

// Read staged chunk from LDS ring into registers (conflict-free ds_read_b128:
// consecutive lanes read consecutive 16 B).
#define DSREAD(HV, BUF)                                            \
  {                                                                \
    _Pragma("unroll")                                              \
    for (int t = 0; t < TOK_PER_WAVE; ++t)                         \
      HV[t] = tile[wave][BUF][t][lane];                            \
  }

#define FMA_BLOCK(HV, G)                                           \
  {                                                                \
    _Pragma("unroll")                                              \
    for (int t = 0; t < TOK_PER_WAVE; ++t) {                       \
      _Pragma("unroll")                                            \
      for (int e = 0; e < NEXP; ++e) {                             \
        float a = r[t * NEXP + e];                                 \
        a = fmaf(HV[t].x, G[e].x, a);                              \
        a = fmaf(HV[t].y, G[e].y, a);                              \
        a = fmaf(HV[t].z, G[e].z, a);                              \
        a = fmaf(HV[t].w, G[e].w, a);                              \
        r[t * NEXP + e] = a;                                       \
      }                                                            \
    }                                                              \
  }

__global__ __launch_bounds__(256, 4)
void router_kernel(const float* __restrict__ hs, const float* __restrict__ gw,
                   float* __restrict__ out, float* __restrict__ ws) {
  // Per-wave private hidden ring: 4 waves x 2 bufs x 4 tokens x 64 float4
  // = 32 KB. Wave-private => no barriers in the k-loop.
  __shared__ vfloat4 tile[WAVES_PER_BLOCK][2][TOK_PER_WAVE][64];
  __shared__ float smP[NEXP];
  __shared__ float smC[NEXP];
  if (threadIdx.x < NEXP) { smP[threadIdx.x] = 0.f; smC[threadIdx.x] = 0.f; }
  __syncthreads();

  const int lane = threadIdx.x & 63;
  const int wave = threadIdx.x >> 6;
  const int tokenBase = (blockIdx.x * WAVES_PER_BLOCK + wave) * TOK_PER_WAVE;

  const vfloat4* __restrict__ h4p = reinterpret_cast<const vfloat4*>(hs);
  const vfloat4* __restrict__ g4p = reinterpret_cast<const vfloat4*>(gw);

  float r[TOK_PER_WAVE * NEXP];  // 32 accumulators: r[t*8+e]
#pragma unroll
  for (int i = 0; i < TOK_PER_WAVE * NEXP; ++i) r[i] = 0.f;

  // Prologue: stage chunks 0 and 1; wait for chunk 0 only (4 youngest =
  // stage_1 stay in flight).
  STAGE(0, 0)
  STAGE(1, 1)
  asm volatile("s_waitcnt vmcnt(4)" ::: "memory");
  __builtin_amdgcn_sched_barrier(0);

  // Main loop: chunks 0..13 (each restages +2 ahead). Counted vmcnt only.
  for (int k = 0; k < ITERS - 2; ++k) {
    const int buf = k & 1;
    // Gate chunk k from global (L2-warm, 128 KB total) — oldest vmem this
    // iteration, so the counted wait below completes it without draining
    // the youngest stage.
    vfloat4 g[NEXP];
#pragma unroll
    for (int e = 0; e < NEXP; ++e) g[e] = g4p[e * H4 + lane + 64 * k];
    __builtin_amdgcn_sched_barrier(0);
    // Hidden chunk k from the ring (staged 2 iterations ago).
    vfloat4 hv[TOK_PER_WAVE];
    DSREAD(hv, buf)
    // WAR fence: data must be in VGPRs before this buffer is restaged.
    asm volatile("s_waitcnt lgkmcnt(0)" ::: "memory");
    __builtin_amdgcn_sched_barrier(0);
    STAGE(buf, k + 2)
    __builtin_amdgcn_sched_barrier(0);
    // gate_k and stage_{k+1} complete; stage_{k+2} (4 youngest) in flight.
    asm volatile("s_waitcnt vmcnt(4)" ::: "memory");
    __builtin_amdgcn_sched_barrier(0);
    FMA_BLOCK(hv, g)
  }
  // Tail: chunks 14, 15 — nothing left to stage; drain fully.
  for (int k = ITERS - 2; k < ITERS; ++k) {
    const int buf = k & 1;
    vfloat4 g[NEXP];
#pragma unroll
    for (int e = 0; e < NEXP; ++e) g[e] = g4p[e * H4 + lane + 64 * k];
    __builtin_amdgcn_sched_barrier(0);
    vfloat4 hv[TOK_PER_WAVE];
    DSREAD(hv, buf)
    asm volatile("s_waitcnt vmcnt(0) lgkmcnt(0)" ::: "memory");
    __builtin_amdgcn_sched_barrier(0);
    FMA_BLOCK(hv, g)
  }

  // 32-value butterfly within each 32-lane half: lane l ends holding the
  // half-sum of value (l&31) (token = (l&31)>>3, expert = l&7).
  RED_STEP(16, 16)
  RED_STEP(8, 8)
  RED_STEP(4, 4)
  RED_STEP(2, 2)
  float red;
  {
    const bool hi = (lane & 1) != 0;
    float send = hi ? r[0] : r[1];
    float recv = __shfl_xor(send, 1, 64);
    red = (hi ? r[1] : r[0]) + recv;
  }
  // Fold the two 32-lane halves: every lane now holds the full 64-lane sum
  // of value (lane&31).
  red += __shfl_xor(red, 32, 64);

  // Lanes 0..31 store one logit each: 128 B contiguous per wave.
  if (lane < 32) out[OFF_LG + tokenBase * NEXP + lane] = red;

  // Gather the 8 logits of this lane-group's token (source lanes 0..31 hold
  // full sums; all 64 lanes execute the shfl).
  float le[NEXP];
  const int groupBase = lane & 24;
#pragma unroll
  for (int e = 0; e < NEXP; ++e) le[e] = __shfl(red, groupBase + e, 64);

  if (lane < 32 && (lane & 7) == 0) {
    const int tok = tokenBase + (lane >> 3);
    // top-1 (strict > => lowest index wins ties, like lax.top_k)
    int i1 = 0; float m1 = le[0];
#pragma unroll
    for (int e = 1; e < NEXP; ++e) {
      if (le[e] > m1) { m1 = le[e]; i1 = e; }
    }
    int i2 = (i1 == 0) ? 1 : 0; float m2 = le[i2];
#pragma unroll
    for (int e = 0; e < NEXP; ++e) {
      if (e != i1 && le[e] > m2) { m2 = le[e]; i2 = e; }
    }
    // full softmax (max-shifted)
    float p[NEXP];
    float psum = 0.f;
#pragma unroll
    for (int e = 0; e < NEXP; ++e) { p[e] = expf(le[e] - m1); psum += p[e]; }
    const float inv = 1.0f / psum;
#pragma unroll
    for (int e = 0; e < NEXP; ++e) atomicAdd(&smP[e], p[e] * inv);
    atomicAdd(&smC[i1], 1.0f);

    // normalized top-2 routing weights: p[i1] = 1, p[i2] = exp(m2-m1)
    const float w1 = p[i1], w2 = p[i2];
    const float rs = 1.0f / (w1 + w2);
    out[OFF_RW + tok * 2 + 0] = w1 * rs;
    out[OFF_RW + tok * 2 + 1] = w2 * rs;
    out[OFF_SE + tok * 2 + 0] = (float)i1;
    out[OFF_SE + tok * 2 + 1] = (float)i2;
  }

  __syncthreads();
  // Per-block partials: row-major [16 rows][NBLOCKS]; plain stores, no
  // init needed (d_ws is poison — we overwrite every slot we later read).
  if (threadIdx.x < 2 * NEXP) {
    const float v = (threadIdx.x < NEXP) ? smP[threadIdx.x]
                                         : smC[threadIdx.x - NEXP];
    ws[threadIdx.x * NBLOCKS + blockIdx.x] = v;
  }
}

__global__ __launch_bounds__(1024)
void aux_kernel(const float* __restrict__ ws, float* __restrict__ out) {
  __shared__ float sm[2 * NEXP];
  const int lane = threadIdx.x & 63;
  const int w = threadIdx.x >> 6;  // 16 waves, one per partial row
  float s = 0.f;
#pragma unroll
  for (int i = 0; i < NBLOCKS / 64; ++i) s += ws[w * NBLOCKS + lane + 64 * i];
#pragma unroll
  for (int off = 32; off > 0; off >>= 1) s += __shfl_xor(s, off, 64);
  if (lane == 0) sm[w] = s;
  __syncthreads();
  if (threadIdx.x == 0) {
    const float invT = 1.0f / (float)T_TOKENS;
    float acc = 0.f;
#pragma unroll
    for (int e = 0; e < NEXP; ++e) {
      const float f = sm[NEXP + e] * invT;  // mean one-hot(top1)
      const float P = sm[e] * invT;         // mean probs
      acc += f * P;
    }
    out[OFF_AUX] = 0.01f * (float)NEXP * acc;
  }
}

extern "C" void kernel_launch(void* const* d_in, const int* in_sizes, int n_in,
                              void* d_out, int out_size, void* d_ws, size_t ws_size,
                              hipStream_t stream) {
  const float* hs = (const float*)d_in[0];   // (16384, 4096) f32
  const float* gw = (const float*)d_in[1];   // (8, 4096) f32
  float* out = (float*)d_out;
  float* ws  = (float*)d_ws;

  router_kernel<<<NBLOCKS, 256, 0, stream>>>(hs, gw, out, ws);
  aux_kernel<<<1, 1024, 0, stream>>>(ws, out);
}